// Round 8
// baseline (15924.756 us; speedup 1.0000x reference)
//
#include <hip/hip_runtime.h>
#include <hip/hip_bf16.h>

#define DIM 16
#define N_ATM 131072
#define N_BND 1048576
#define N_ANG 2097152
#define N_GRAPHS 256
#define PI_F 3.14159265358979323846f

typedef __hip_bfloat16 bf16;

__device__ __forceinline__ int clampi(int v, int lo, int hi) {
    return v < lo ? lo : (v > hi ? hi : v);
}
__device__ __forceinline__ float b2f(bf16 v) { return __bfloat162float(v); }
__device__ __forceinline__ float sigmoidf_(float x) { return 1.0f / (1.0f + __expf(-x)); }
__device__ __forceinline__ float siluf_(float x) { return x / (1.0f + __expf(-x)); }

__device__ __forceinline__ float loadF(const void* p, long long i, int isbf) {
    return isbf ? b2f(((const bf16*)p)[i]) : ((const float*)p)[i];
}
__device__ __forceinline__ float bfbits2f(unsigned lo16) {
    union { unsigned u; float f; } c; c.u = lo16 << 16; return c.f;
}
__device__ __forceinline__ unsigned f2bfbits(float f) {
    union { float f; unsigned u; } c; c.f = f;
    unsigned u = c.u + 0x7FFFu + ((c.u >> 16) & 1u);  // RNE
    return u >> 16;
}

template <typename T> struct VecIO;
template <> struct VecIO<float> {
    static __device__ __forceinline__ void load16(const float* p, float* r) {
        const float4* q = (const float4*)p;
#pragma unroll
        for (int i = 0; i < 4; i++) { float4 v = q[i]; r[4*i]=v.x; r[4*i+1]=v.y; r[4*i+2]=v.z; r[4*i+3]=v.w; }
    }
    static __device__ __forceinline__ void store16(float* p, const float* r) {
        float4* q = (float4*)p;
#pragma unroll
        for (int i = 0; i < 4; i++) q[i] = make_float4(r[4*i], r[4*i+1], r[4*i+2], r[4*i+3]);
    }
};
template <> struct VecIO<bf16> {
    static __device__ __forceinline__ void load16(const bf16* p, float* r) {
        uint4 a = ((const uint4*)p)[0];
        uint4 b = ((const uint4*)p)[1];
        unsigned w[8] = {a.x, a.y, a.z, a.w, b.x, b.y, b.z, b.w};
#pragma unroll
        for (int i = 0; i < 8; i++) {
            r[2*i] = bfbits2f(w[i] & 0xFFFFu);
            union { unsigned u; float f; } c; c.u = w[i] & 0xFFFF0000u;
            r[2*i+1] = c.f;
        }
    }
    static __device__ __forceinline__ void store16(bf16* p, const float* r) {
        unsigned w[8];
#pragma unroll
        for (int i = 0; i < 8; i++)
            w[i] = f2bfbits(r[2*i]) | (f2bfbits(r[2*i+1]) << 16);
        ((uint4*)p)[0] = make_uint4(w[0], w[1], w[2], w[3]);
        ((uint4*)p)[1] = make_uint4(w[4], w[5], w[6], w[7]);
    }
};

// ---------- utility ----------
__global__ void __launch_bounds__(256) k_zero_int(int* __restrict__ p, int n) {
    int i = blockIdx.x * 256 + threadIdx.x;
    if (i < n) p[i] = 0;
}
__global__ void __launch_bounds__(256) k_zero4(float4* __restrict__ p, int n4) {
    int i = blockIdx.x * 256 + threadIdx.x;
    if (i < n4) p[i] = make_float4(0.f, 0.f, 0.f, 0.f);
}

// flags[0]=1 if float tensors are bf16; flags[1]=1 if mask is byte-bools
__global__ void __launch_bounds__(256) k_detect(const void* lng, const unsigned* __restrict__ mask,
                                                int* flags) {
    int i = blockIdx.x * 256 + threadIdx.x;
    if (i == 0) flags[0] = (*(const unsigned*)lng == 0x3F803F80u) ? 1 : 0;
    int bad = 0;
    for (int j = i; j < 512 * 1024; j += 512 * 256)
        if (mask[j] > 1u) bad = 1;
    if (bad) atomicOr(&flags[1], 1);
}

__global__ void k_cvt_any(const void* __restrict__ src, float* __restrict__ dst, int n,
                          const int* __restrict__ flags) {
    int i = blockIdx.x * blockDim.x + threadIdx.x;
    if (i < n) dst[i] = loadF(src, i, flags[0]);
}

// ---------- CSR build ----------
__global__ void __launch_bounds__(256) k_count(const int* __restrict__ dst, int* __restrict__ cnt,
                                               int E, int n) {
    int i = blockIdx.x * 256 + threadIdx.x;
    if (i >= E) return;
    atomicAdd(&cnt[clampi(dst[i], 0, n - 1)], 1);
}
__global__ void __launch_bounds__(256) k_scan_local(const int* __restrict__ cnt, int* __restrict__ ofs,
                                                    int* __restrict__ bsum, int n) {
    __shared__ int s[256];
    int t = threadIdx.x, i = blockIdx.x * 256 + t;
    int v = (i < n) ? cnt[i] : 0;
    s[t] = v; __syncthreads();
    for (int o = 1; o < 256; o <<= 1) {
        int add = (t >= o) ? s[t - o] : 0;
        __syncthreads();
        s[t] += add;
        __syncthreads();
    }
    if (i < n) ofs[i] = s[t] - v;
    if (t == 255) bsum[blockIdx.x] = s[255];
}
__global__ void __launch_bounds__(256) k_scan_bsum(int* __restrict__ bsum, int nb) {
    __shared__ int s[256];
    __shared__ int run;
    int t = threadIdx.x;
    if (t == 0) run = 0;
    __syncthreads();
    for (int base = 0; base < nb; base += 256) {
        int i = base + t;
        int v = (i < nb) ? bsum[i] : 0;
        s[t] = v; __syncthreads();
        for (int o = 1; o < 256; o <<= 1) {
            int add = (t >= o) ? s[t - o] : 0;
            __syncthreads();
            s[t] += add;
            __syncthreads();
        }
        if (i < nb) bsum[i] = run + s[t] - v;
        __syncthreads();
        if (t == 0) run += s[255];
        __syncthreads();
    }
}
__global__ void __launch_bounds__(256) k_scan_add(int* __restrict__ ofs, const int* __restrict__ bsum,
                                                  int* __restrict__ cursor, int n) {
    int i = blockIdx.x * 256 + threadIdx.x;
    if (i < n) { int v = ofs[i] + bsum[blockIdx.x]; ofs[i] = v; cursor[i] = v; }
}
__global__ void __launch_bounds__(256) k_scatter2(
    const int* __restrict__ src, const int* __restrict__ dst, int* __restrict__ cur,
    int* __restrict__ pos, int* __restrict__ srcP, int* __restrict__ dstP,
    int* __restrict__ eidP, int E, int n, int ns)
{
    int i = blockIdx.x * 256 + threadIdx.x;
    if (i >= E) return;
    int d = clampi(dst[i], 0, n - 1);
    int s = clampi(src[i], 0, ns - 1);
    int p = atomicAdd(&cur[d], 1);
    p = clampi(p, 0, E - 1);            // defensive: never write out of slot range
    srcP[p] = s; dstP[p] = d;
    if (pos)  pos[i] = p;
    if (eidP) eidP[p] = i;
}

// ---------- encoders ----------
__global__ void __launch_bounds__(256) k_enc_atm(
    const int* __restrict__ sp_in,
    const void* W1, const void* b1, const void* W2, const void* b2,
    const void* g, const void* be, const int* __restrict__ flags,
    float* __restrict__ out)
{
    __shared__ float sW1[256], sW2[256], sb1[16], sb2[16], sg[16], sbe[16];
    int t = threadIdx.x, isbf = flags[0];
    sW1[t] = loadF(W1, t, isbf); sW2[t] = loadF(W2, t, isbf);
    if (t < 16) { sb1[t]=loadF(b1,t,isbf); sb2[t]=loadF(b2,t,isbf); sg[t]=loadF(g,t,isbf); sbe[t]=loadF(be,t,isbf); }
    __syncthreads();
    int i = blockIdx.x * 256 + t;
    if (i >= N_ATM) return;
    int sp = clampi(sp_in[i], 0, 15);
    float h[16];
#pragma unroll
    for (int j = 0; j < 16; j++) h[j] = siluf_(sW1[sp * 16 + j] + sb1[j]);
    float o[16]; float mu = 0.f;
#pragma unroll
    for (int j = 0; j < 16; j++) {
        float a = sb2[j];
#pragma unroll
        for (int k = 0; k < 16; k++) a += h[k] * sW2[k * 16 + j];
        o[j] = a; mu += a;
    }
    mu *= (1.f / 16.f);
    float var = 0.f;
#pragma unroll
    for (int j = 0; j < 16; j++) { float d = o[j] - mu; var += d * d; }
    var *= (1.f / 16.f);
    float r = rsqrtf(var + 1e-5f);
    float ov[16];
#pragma unroll
    for (int j = 0; j < 16; j++) ov[j] = (o[j] - mu) * r * sg[j] + sbe[j];
    VecIO<float>::store16(out + (long long)i * 16, ov);
}

template <typename TO>
__global__ void __launch_bounds__(256) k_enc_bnd(
    const void* __restrict__ xb,
    const void* W1, const void* b1, const void* W2, const void* b2,
    const void* g, const void* be, const int* __restrict__ flags,
    TO* __restrict__ out)
{
    __shared__ float sW1[256], sW2[256], sb1[16], sb2[16], sg[16], sbe[16];
    int t = threadIdx.x, isbf = flags[0];
    sW1[t] = loadF(W1, 256 + t, isbf); sW2[t] = loadF(W2, 256 + t, isbf);
    if (t < 16) { sb1[t]=loadF(b1,16+t,isbf); sb2[t]=loadF(b2,16+t,isbf); sg[t]=loadF(g,16+t,isbf); sbe[t]=loadF(be,16+t,isbf); }
    __syncthreads();
    int i = blockIdx.x * 256 + t;
    if (i >= N_BND) return;
    float x = loadF(xb, i, isbf) + 1e-5f;
    const float c = 0.6324555320336759f; // sqrt(2/5)
    float inv = c / x;
    float feat[16];
#pragma unroll
    for (int k = 0; k < 16; k++) feat[k] = __sinf((float)(k + 1) * PI_F * x * 0.2f) * inv;
    float h[16];
#pragma unroll
    for (int j = 0; j < 16; j++) {
        float a = sb1[j];
#pragma unroll
        for (int k = 0; k < 16; k++) a += feat[k] * sW1[k * 16 + j];
        h[j] = siluf_(a);
    }
    float o[16]; float mu = 0.f;
#pragma unroll
    for (int j = 0; j < 16; j++) {
        float a = sb2[j];
#pragma unroll
        for (int k = 0; k < 16; k++) a += h[k] * sW2[k * 16 + j];
        o[j] = a; mu += a;
    }
    mu *= (1.f / 16.f);
    float var = 0.f;
#pragma unroll
    for (int j = 0; j < 16; j++) { float d = o[j] - mu; var += d * d; }
    var *= (1.f / 16.f);
    float r = rsqrtf(var + 1e-5f);
    float ov[16];
#pragma unroll
    for (int j = 0; j < 16; j++) ov[j] = (o[j] - mu) * r * sg[j] + sbe[j];
    VecIO<TO>::store16(out + (long long)i * 16, ov);
}

// angle encoder: row = pos ? pos[i] : i  (bf16 storage)
__global__ void __launch_bounds__(256) k_enc_ang(
    const void* __restrict__ xa, const void* __restrict__ mask,
    const void* W1, const void* b1, const void* W2, const void* b2,
    const void* g, const void* be, const int* __restrict__ flags,
    const int* __restrict__ pos, bf16* __restrict__ out)
{
    __shared__ float sW1[512], sW2[512], sb1[32], sb2[32], sg[32], sbe[32];
    int t = threadIdx.x, isbf = flags[0], mbyte = flags[1];
    for (int i = t; i < 512; i += 256) { sW1[i] = loadF(W1, 512 + i, isbf); sW2[i] = loadF(W2, 512 + i, isbf); }
    if (t < 32) { sb1[t]=loadF(b1,32+t,isbf); sb2[t]=loadF(b2,32+t,isbf); sg[t]=loadF(g,32+t,isbf); sbe[t]=loadF(be,32+t,isbf); }
    __syncthreads();
    int i = blockIdx.x * 256 + t;
    if (i >= N_ANG) return;
    int m = mbyte ? (((const unsigned char*)mask)[i] != 0) : (((const int*)mask)[i] != 0);
    float x = loadF(xa, i, isbf);
    float gam = m ? 2.3873241463784303f : 4.7746482927568605f;   // 15/(2pi) : 15/pi
    float c0  = m ? -PI_F : 0.0f;
    float dc  = m ? 0.41887902047863906f : 0.20943951023931953f; // 2pi/15 : pi/15
    int wo = m * 256, vo = m * 16;
    float feat[16];
#pragma unroll
    for (int k = 0; k < 16; k++) {
        float d = gam * (x - (c0 + (float)k * dc));
        feat[k] = __expf(-d * d);
    }
    float h[16];
#pragma unroll
    for (int j = 0; j < 16; j++) {
        float a = sb1[vo + j];
#pragma unroll
        for (int k = 0; k < 16; k++) a += feat[k] * sW1[wo + k * 16 + j];
        h[j] = siluf_(a);
    }
    float o[16]; float mu = 0.f;
#pragma unroll
    for (int j = 0; j < 16; j++) {
        float a = sb2[vo + j];
#pragma unroll
        for (int k = 0; k < 16; k++) a += h[k] * sW2[wo + k * 16 + j];
        o[j] = a; mu += a;
    }
    mu *= (1.f / 16.f);
    float var = 0.f;
#pragma unroll
    for (int j = 0; j < 16; j++) { float d = o[j] - mu; var += d * d; }
    var *= (1.f / 16.f);
    float r = rsqrtf(var + 1e-5f);
    float ov[16];
#pragma unroll
    for (int j = 0; j < 16; j++) ov[j] = (o[j] - mu) * r * sg[vo + j] + sbe[vo + j];
    long long row = pos ? (long long)clampi(pos[i], 0, N_ANG - 1) : (long long)i;
    VecIO<bf16>::store16(out + row * 16, ov);
}

// ---------- CSR conv: edge kernel (1 thread/edge) ----------
template <typename TX, typename TE, bool PERM>
__global__ void __launch_bounds__(256) k_econv(
    const TX* __restrict__ x, TE* __restrict__ e,
    const int* __restrict__ srcP, const int* __restrict__ dstP,
    const int* __restrict__ eidP,
    const float* __restrict__ W, const float* __restrict__ B, const float* __restrict__ L,
    bf16* __restrict__ scratch, int E, int nn)
{
    __shared__ float sW[1280], sB[16], sLg[16], sLb[16];
    int t = threadIdx.x;
    for (int i = t; i < 1280; i += 256) sW[i] = W[i];
    if (t < 16) { sB[t] = B[t]; sLg[t] = L[32 + t]; sLb[t] = L[48 + t]; }
    __syncthreads();
    int p = blockIdx.x * 256 + t;
    if (p >= E) return;
    int s = clampi(srcP[p], 0, nn - 1);
    int d = clampi(dstP[p], 0, nn - 1);
    long long erow;
    if constexpr (PERM) erow = (long long)p;
    else                erow = (long long)clampi(eidP[p], 0, E - 1);
    float xs[16], xd[16], ev[16];
    VecIO<TX>::load16(x + (long long)s * 16, xs);
    VecIO<TX>::load16(x + (long long)d * 16, xd);
    VecIO<TE>::load16(e + erow * 16, ev);
    float z[16], mm[16];
#pragma unroll
    for (int j = 0; j < 16; j++) { z[j] = sB[j]; mm[j] = 0.f; }
#pragma unroll
    for (int k = 0; k < 16; k++) {
        float a = xs[k], c = xd[k], q = ev[k];
#pragma unroll
        for (int j = 0; j < 16; j++) {
            z[j] += a * sW[k * 16 + j] + c * sW[256 + k * 16 + j] + q * sW[512 + k * 16 + j];
            mm[j] += a * sW[1024 + k * 16 + j];
        }
    }
    float mu = 0.f;
#pragma unroll
    for (int j = 0; j < 16; j++) mu += z[j];
    mu *= (1.f / 16.f);
    float var = 0.f;
#pragma unroll
    for (int j = 0; j < 16; j++) { float dd = z[j] - mu; var += dd * dd; }
    var *= (1.f / 16.f);
    float r = rsqrtf(var + 1e-5f);
    float eo[16];
#pragma unroll
    for (int j = 0; j < 16; j++)
        eo[j] = ev[j] + siluf_((z[j] - mu) * r * sLg[j] + sLb[j]);
    VecIO<TE>::store16(e + erow * 16, eo);
    unsigned w[16];
#pragma unroll
    for (int i = 0; i < 8; i++) {
        float a0 = sigmoidf_(z[2*i]);
        float a1 = sigmoidf_(z[2*i+1]);
        w[i]     = f2bfbits(a0 * mm[2*i]) | (f2bfbits(a1 * mm[2*i+1]) << 16);
        w[8 + i] = f2bfbits(a0)           | (f2bfbits(a1) << 16);
    }
    uint4* sp4 = (uint4*)(scratch + (long long)p * 32);
    sp4[0] = make_uint4(w[0],  w[1],  w[2],  w[3]);
    sp4[1] = make_uint4(w[4],  w[5],  w[6],  w[7]);
    sp4[2] = make_uint4(w[8],  w[9],  w[10], w[11]);
    sp4[3] = make_uint4(w[12], w[13], w[14], w[15]);
}

// ---------- CSR conv: node kernel ----------
template <typename TX>
__global__ void __launch_bounds__(256) k_nconv(
    TX* __restrict__ x,
    const int* __restrict__ ofs, const int* __restrict__ endo,
    const float* __restrict__ W, const float* __restrict__ B, const float* __restrict__ L,
    const bf16* __restrict__ scratch, int n, int Emax)
{
    __shared__ float sW[256], sB[16], sLg[16], sLb[16];
    int t = threadIdx.x;
    sW[t] = W[768 + t];
    if (t < 16) { sB[t] = B[16 + t]; sLg[t] = L[t]; sLb[t] = L[16 + t]; }
    __syncthreads();
    int d = blockIdx.x * 256 + t;
    if (d >= n) return;
    float xv[16];
    VecIO<TX>::load16(x + (long long)d * 16, xv);
    float num[16], den[16];
#pragma unroll
    for (int j = 0; j < 16; j++) { num[j] = 0.f; den[j] = 0.f; }
    int p0 = clampi(ofs[d], 0, Emax);
    int p1 = clampi(endo[d], p0, Emax);
    for (int p = p0; p < p1; p++) {
        const uint4* q = (const uint4*)(scratch + (long long)p * 32);
        uint4 q0 = q[0], q1 = q[1], q2 = q[2], q3 = q[3];
        unsigned w[16] = {q0.x,q0.y,q0.z,q0.w, q1.x,q1.y,q1.z,q1.w,
                          q2.x,q2.y,q2.z,q2.w, q3.x,q3.y,q3.z,q3.w};
#pragma unroll
        for (int i = 0; i < 8; i++) {
            num[2*i]   += bfbits2f(w[i] & 0xFFFFu);
            num[2*i+1] += bfbits2f(w[i] >> 16);
            den[2*i]   += bfbits2f(w[8+i] & 0xFFFFu);
            den[2*i+1] += bfbits2f(w[8+i] >> 16);
        }
    }
    float tt[16]; float mu = 0.f;
#pragma unroll
    for (int j = 0; j < 16; j++) {
        float a = sB[j] + num[j] / (den[j] + 1e-5f);
#pragma unroll
        for (int k = 0; k < 16; k++) a += xv[k] * sW[k * 16 + j];
        tt[j] = a; mu += a;
    }
    mu *= (1.f / 16.f);
    float var = 0.f;
#pragma unroll
    for (int j = 0; j < 16; j++) { float dd = tt[j] - mu; var += dd * dd; }
    var *= (1.f / 16.f);
    float r = rsqrtf(var + 1e-5f);
    float ov[16];
#pragma unroll
    for (int j = 0; j < 16; j++)
        ov[j] = xv[j] + siluf_((tt[j] - mu) * r * sLg[j] + sLb[j]);
    VecIO<TX>::store16(x + (long long)d * 16, ov);
}

// ---------- fallback conv: atomic edge + node (proven round-3 path) ----------
template <typename TX, typename TE>
__global__ void __launch_bounds__(256) k_edge_at(
    const TX* __restrict__ x, TE* __restrict__ e,
    const int* __restrict__ src, const int* __restrict__ dst,
    const float* __restrict__ W, const float* __restrict__ B, const float* __restrict__ L,
    float* __restrict__ num, float* __restrict__ den, int E, int nn)
{
    int i = blockIdx.x * 256 + threadIdx.x;
    if (i >= E) return;
    int s = clampi(src[i], 0, nn - 1);
    int d = clampi(dst[i], 0, nn - 1);
    float xs[16], xd[16], ev[16];
    VecIO<TX>::load16(x + (long long)s * 16, xs);
    VecIO<TX>::load16(x + (long long)d * 16, xd);
    VecIO<TE>::load16(e + (long long)i * 16, ev);
    float z[16], mm[16];
#pragma unroll
    for (int j = 0; j < 16; j++) { z[j] = B[j]; mm[j] = 0.f; }
#pragma unroll
    for (int k = 0; k < 16; k++) {
        float a = xs[k], c = xd[k], q = ev[k];
#pragma unroll
        for (int j = 0; j < 16; j++) {
            z[j] += a * W[k * 16 + j] + c * W[256 + k * 16 + j] + q * W[512 + k * 16 + j];
            mm[j] += a * W[1024 + k * 16 + j];
        }
    }
    float* nrow = num + (long long)d * 16;
    float* drow = den + (long long)d * 16;
    float mu = 0.f;
#pragma unroll
    for (int j = 0; j < 16; j++) {
        float sg_ = sigmoidf_(z[j]);
        atomicAdd(&nrow[j], sg_ * mm[j]);
        atomicAdd(&drow[j], sg_);
        mu += z[j];
    }
    mu *= (1.f / 16.f);
    float var = 0.f;
#pragma unroll
    for (int j = 0; j < 16; j++) { float dd = z[j] - mu; var += dd * dd; }
    var *= (1.f / 16.f);
    float r = rsqrtf(var + 1e-5f);
    float ov[16];
#pragma unroll
    for (int j = 0; j < 16; j++)
        ov[j] = ev[j] + siluf_((z[j] - mu) * r * L[32 + j] + L[48 + j]);
    VecIO<TE>::store16(e + (long long)i * 16, ov);
}

template <typename TX>
__global__ void __launch_bounds__(256) k_node_at(
    TX* __restrict__ x,
    const float* __restrict__ W, const float* __restrict__ B, const float* __restrict__ L,
    const float* __restrict__ num, const float* __restrict__ den, int n)
{
    int i = blockIdx.x * 256 + threadIdx.x;
    if (i >= n) return;
    float xv[16], nv[16], dv[16];
    VecIO<TX>::load16(x + (long long)i * 16, xv);
    VecIO<float>::load16(num + (long long)i * 16, nv);
    VecIO<float>::load16(den + (long long)i * 16, dv);
    float t[16]; float mu = 0.f;
#pragma unroll
    for (int j = 0; j < 16; j++) {
        float a = B[16 + j] + nv[j] / (dv[j] + 1e-5f);
#pragma unroll
        for (int k = 0; k < 16; k++) a += xv[k] * W[768 + k * 16 + j];
        t[j] = a; mu += a;
    }
    mu *= (1.f / 16.f);
    float var = 0.f;
#pragma unroll
    for (int j = 0; j < 16; j++) { float dd = t[j] - mu; var += dd * dd; }
    var *= (1.f / 16.f);
    float r = rsqrtf(var + 1e-5f);
    float ov[16];
#pragma unroll
    for (int j = 0; j < 16; j++)
        ov[j] = xv[j] + siluf_((t[j] - mu) * r * L[j] + L[16 + j]);
    VecIO<TX>::store16(x + (long long)i * 16, ov);
}

// ---------- pooling (atomic-free) ----------
__global__ void __launch_bounds__(256) k_pool2(
    const float* __restrict__ h, const int* __restrict__ batch, float* __restrict__ pooled)
{
    int g = blockIdx.x;
    int lo = 0, hi = N_ATM;
    while (lo < hi) { int m = (lo + hi) >> 1; if (batch[m] < g) lo = m + 1; else hi = m; }
    int s0 = lo;
    lo = 0; hi = N_ATM;
    while (lo < hi) { int m = (lo + hi) >> 1; if (batch[m] < g + 1) lo = m + 1; else hi = m; }
    int s1 = lo;
    float acc[16];
#pragma unroll
    for (int j = 0; j < 16; j++) acc[j] = 0.f;
    for (int i = s0 + threadIdx.x; i < s1; i += 256) {
        float v[16];
        VecIO<float>::load16(h + (long long)i * 16, v);
#pragma unroll
        for (int j = 0; j < 16; j++) acc[j] += v[j];
    }
#pragma unroll
    for (int j = 0; j < 16; j++)
        for (int o = 32; o > 0; o >>= 1) acc[j] += __shfl_down(acc[j], o, 64);
    __shared__ float red[4][16];
    int wv = threadIdx.x >> 6, ln = threadIdx.x & 63;
    if (ln == 0)
#pragma unroll
        for (int j = 0; j < 16; j++) red[wv][j] = acc[j];
    __syncthreads();
    if (threadIdx.x < 16)
        pooled[g * 16 + threadIdx.x] = red[0][threadIdx.x] + red[1][threadIdx.x]
                                     + red[2][threadIdx.x] + red[3][threadIdx.x];
}

// ---------- head ----------
__global__ void __launch_bounds__(256) k_head(
    const float* __restrict__ pooled, const void* __restrict__ fp,
    const void* l1W, const void* l1b, const void* l2W, const void* l2b,
    const int* __restrict__ flags, void* __restrict__ out)
{
    __shared__ float sW[18 * 16], sb[16], s2W[16];
    int t = threadIdx.x, isbf = flags[0];
    for (int i = t; i < 288; i += 256) sW[i] = loadF(l1W, i, isbf);
    if (t < 16) { sb[t] = loadF(l1b, t, isbf); s2W[t] = loadF(l2W, t, isbf); }
    __syncthreads();
    int g = t;
    if (g >= N_GRAPHS) return;
    float in[18];
#pragma unroll
    for (int j = 0; j < 16; j++) in[j] = pooled[g * 16 + j];
    in[16] = loadF(fp, 2 * g, isbf);
    in[17] = loadF(fp, 2 * g + 1, isbf);
    float acc = loadF(l2b, 0, isbf);
#pragma unroll
    for (int j = 0; j < 16; j++) {
        float h = sb[j];
#pragma unroll
        for (int k = 0; k < 18; k++) h += in[k] * sW[k * 16 + j];
        h = (h > 0.f) ? h : 0.01f * h;
        acc += h * s2W[j];
    }
    if (isbf) ((bf16*)out)[g] = __float2bfloat16(acc);
    else      ((float*)out)[g] = acc;
}

// ================= pipelines =================
struct Args {
    const int *x_atm, *eiG, *eiA, *batch;
    const void *x_bnd, *x_ang, *mask, *fp;
    const void *eW1, *eb1, *eW2, *eb2, *elg, *elb;
    const void *convW, *convB, *convLN, *l1W, *l1b, *l2W, *l2b;
};
static Args unpack(void* const* d_in) {
    Args a;
    a.x_atm = (const int*)d_in[0]; a.x_bnd = d_in[1]; a.x_ang = d_in[2]; a.mask = d_in[3];
    a.eiG = (const int*)d_in[4]; a.eiA = (const int*)d_in[5]; a.batch = (const int*)d_in[6];
    a.fp = d_in[7]; a.eW1 = d_in[8]; a.eb1 = d_in[9]; a.eW2 = d_in[10]; a.eb2 = d_in[11];
    a.elg = d_in[12]; a.elb = d_in[13]; a.convW = d_in[14]; a.convB = d_in[15];
    a.convLN = d_in[16]; a.l1W = d_in[17]; a.l1b = d_in[18]; a.l2W = d_in[19]; a.l2b = d_in[20];
    return a;
}

// CSR (fast) pipeline; TB = h_bnd storage
template <typename TB>
static void run_csr(const Args& a, void* d_out, void* d_ws, hipStream_t stream) {
    const size_t NA16 = (size_t)N_ATM * 16;
    const size_t NB16 = (size_t)N_BND * 16;
    const size_t NG16 = (size_t)N_ANG * 16;
    char* p = (char*)d_ws;
    int*   flags  = (int*)p;   p += 64 * 4;
    float* cw     = (float*)p; p += 7680 * 4;
    float* cb     = (float*)p; p += 192 * 4;
    float* cln    = (float*)p; p += 384 * 4;
    float* pooled = (float*)p; p += 4096 * 4;
    int*   bsum   = (int*)p;   p += 4096 * 4;
    int*   cntB   = (int*)p;   p += (size_t)N_BND * 4;
    int*   ofsB   = (int*)p;   p += (size_t)N_BND * 4;
    int*   srcB   = (int*)p;   p += (size_t)N_ANG * 4;
    int*   dstB   = (int*)p;   p += (size_t)N_ANG * 4;
    int*   cntA   = (int*)p;   p += (size_t)N_ATM * 4;
    int*   ofsA   = (int*)p;   p += (size_t)N_ATM * 4;
    int*   eidA   = (int*)p;   p += (size_t)N_BND * 4;
    int*   srcAp  = (int*)p;   p += (size_t)N_BND * 4;
    int*   dstAp  = (int*)p;   p += (size_t)N_BND * 4;
    float* h_atm  = (float*)p; p += NA16 * 4;
    TB*    h_bnd  = (TB*)p;    p += NB16 * sizeof(TB);
    bf16*  h_ang  = (bf16*)p;  p += NG16 * 2;
    int*   posB    = (int*)p;            // union with scratch (posB dead before scratch born)
    bf16*  scratch = (bf16*)p;

    k_zero_int<<<1, 64, 0, stream>>>(flags, 64);
    k_detect<<<512, 256, 0, stream>>>(a.elg, (const unsigned*)a.mask, flags);
    k_cvt_any<<<30, 256, 0, stream>>>(a.convW, cw, 7680, flags);
    k_cvt_any<<<1, 256, 0, stream>>>(a.convB, cb, 192, flags);
    k_cvt_any<<<2, 256, 0, stream>>>(a.convLN, cln, 384, flags);

    {   // CSR line graph
        const int* srcE = a.eiA; const int* dstE = a.eiA + N_ANG;
        k_zero_int<<<N_BND / 256, 256, 0, stream>>>(cntB, N_BND);
        k_count<<<N_ANG / 256, 256, 0, stream>>>(dstE, cntB, N_ANG, N_BND);
        k_scan_local<<<N_BND / 256, 256, 0, stream>>>(cntB, ofsB, bsum, N_BND);
        k_scan_bsum<<<1, 256, 0, stream>>>(bsum, N_BND / 256);
        k_scan_add<<<N_BND / 256, 256, 0, stream>>>(ofsB, bsum, cntB, N_BND);
        k_scatter2<<<N_ANG / 256, 256, 0, stream>>>(srcE, dstE, cntB, posB, srcB, dstB,
                                                    (int*)nullptr, N_ANG, N_BND, N_BND);
    }
    {   // CSR atom graph
        const int* srcE = a.eiG; const int* dstE = a.eiG + N_BND;
        k_zero_int<<<N_ATM / 256, 256, 0, stream>>>(cntA, N_ATM);
        k_count<<<N_BND / 256, 256, 0, stream>>>(dstE, cntA, N_BND, N_ATM);
        k_scan_local<<<N_ATM / 256, 256, 0, stream>>>(cntA, ofsA, bsum, N_ATM);
        k_scan_bsum<<<1, 256, 0, stream>>>(bsum, N_ATM / 256);
        k_scan_add<<<N_ATM / 256, 256, 0, stream>>>(ofsA, bsum, cntA, N_ATM);
        k_scatter2<<<N_BND / 256, 256, 0, stream>>>(srcE, dstE, cntA, (int*)nullptr, srcAp, dstAp,
                                                    eidA, N_BND, N_ATM, N_ATM);
    }

    k_enc_atm<<<N_ATM / 256, 256, 0, stream>>>(a.x_atm, a.eW1, a.eb1, a.eW2, a.eb2, a.elg, a.elb, flags, h_atm);
    k_enc_bnd<TB><<<N_BND / 256, 256, 0, stream>>>(a.x_bnd, a.eW1, a.eb1, a.eW2, a.eb2, a.elg, a.elb, flags, h_bnd);
    k_enc_ang<<<N_ANG / 256, 256, 0, stream>>>(a.x_ang, a.mask, a.eW1, a.eb1, a.eW2, a.eb2, a.elg, a.elb, flags,
                                               posB, h_ang);

    for (int c = 0; c < 3; c++) {
        const float* Wl = cw + (size_t)(c * 2 + 0) * 1280;
        const float* Bl = cb + (size_t)(c * 2 + 0) * 32;
        const float* Ll = cln + (size_t)(c * 2 + 0) * 64;
        k_econv<TB, bf16, true><<<N_ANG / 256, 256, 0, stream>>>(
            h_bnd, h_ang, srcB, dstB, (const int*)nullptr, Wl, Bl, Ll, scratch, N_ANG, N_BND);
        k_nconv<TB><<<N_BND / 256, 256, 0, stream>>>(h_bnd, ofsB, cntB, Wl, Bl, Ll, scratch, N_BND, N_ANG);

        const float* Wa = cw + (size_t)(c * 2 + 1) * 1280;
        const float* Ba = cb + (size_t)(c * 2 + 1) * 32;
        const float* La = cln + (size_t)(c * 2 + 1) * 64;
        k_econv<float, TB, false><<<N_BND / 256, 256, 0, stream>>>(
            h_atm, h_bnd, srcAp, dstAp, eidA, Wa, Ba, La, scratch, N_BND, N_ATM);
        k_nconv<float><<<N_ATM / 256, 256, 0, stream>>>(h_atm, ofsA, cntA, Wa, Ba, La, scratch, N_ATM, N_BND);
    }

    k_pool2<<<N_GRAPHS, 256, 0, stream>>>(h_atm, a.batch, pooled);
    k_head<<<1, 256, 0, stream>>>(pooled, a.fp, a.l1W, a.l1b, a.l2W, a.l2b, flags, d_out);
}

// Atomic fallback pipeline (round-3 proven structure; bf16 bond/angle storage)
static void run_atomic(const Args& a, void* d_out, void* d_ws, hipStream_t stream) {
    const size_t NA16 = (size_t)N_ATM * 16;
    const size_t NB16 = (size_t)N_BND * 16;
    const size_t NG16 = (size_t)N_ANG * 16;
    char* p = (char*)d_ws;
    int*   flags  = (int*)p;   p += 64 * 4;
    float* cw     = (float*)p; p += 7680 * 4;
    float* cb     = (float*)p; p += 192 * 4;
    float* cln    = (float*)p; p += 384 * 4;
    float* pooled = (float*)p; p += 4096 * 4;
    float* h_atm  = (float*)p; p += NA16 * 4;
    bf16*  h_bnd  = (bf16*)p;  p += NB16 * 2;
    bf16*  h_ang  = (bf16*)p;  p += NG16 * 2;
    float* nd     = (float*)p;   // 2 * NB16 floats

    k_zero_int<<<1, 64, 0, stream>>>(flags, 64);
    k_detect<<<512, 256, 0, stream>>>(a.elg, (const unsigned*)a.mask, flags);
    k_cvt_any<<<30, 256, 0, stream>>>(a.convW, cw, 7680, flags);
    k_cvt_any<<<1, 256, 0, stream>>>(a.convB, cb, 192, flags);
    k_cvt_any<<<2, 256, 0, stream>>>(a.convLN, cln, 384, flags);

    k_enc_atm<<<N_ATM / 256, 256, 0, stream>>>(a.x_atm, a.eW1, a.eb1, a.eW2, a.eb2, a.elg, a.elb, flags, h_atm);
    k_enc_bnd<bf16><<<N_BND / 256, 256, 0, stream>>>(a.x_bnd, a.eW1, a.eb1, a.eW2, a.eb2, a.elg, a.elb, flags, h_bnd);
    k_enc_ang<<<N_ANG / 256, 256, 0, stream>>>(a.x_ang, a.mask, a.eW1, a.eb1, a.eW2, a.eb2, a.elg, a.elb, flags,
                                               (const int*)nullptr, h_ang);

    for (int c = 0; c < 3; c++) {
        const float* Wl = cw + (size_t)(c * 2 + 0) * 1280;
        const float* Bl = cb + (size_t)(c * 2 + 0) * 32;
        const float* Ll = cln + (size_t)(c * 2 + 0) * 64;
        k_zero4<<<(int)(2 * NB16 / 4 / 256), 256, 0, stream>>>((float4*)nd, (int)(2 * NB16 / 4));
        k_edge_at<bf16, bf16><<<N_ANG / 256, 256, 0, stream>>>(
            h_bnd, h_ang, a.eiA, a.eiA + N_ANG, Wl, Bl, Ll, nd, nd + NB16, N_ANG, N_BND);
        k_node_at<bf16><<<N_BND / 256, 256, 0, stream>>>(h_bnd, Wl, Bl, Ll, nd, nd + NB16, N_BND);

        const float* Wa = cw + (size_t)(c * 2 + 1) * 1280;
        const float* Ba = cb + (size_t)(c * 2 + 1) * 32;
        const float* La = cln + (size_t)(c * 2 + 1) * 64;
        k_zero4<<<(int)(2 * NA16 / 4 / 256), 256, 0, stream>>>((float4*)nd, (int)(2 * NA16 / 4));
        k_edge_at<float, bf16><<<N_BND / 256, 256, 0, stream>>>(
            h_atm, h_bnd, a.eiG, a.eiG + N_BND, Wa, Ba, La, nd, nd + NA16, N_BND, N_ATM);
        k_node_at<float><<<N_ATM / 256, 256, 0, stream>>>(h_atm, Wa, Ba, La, nd, nd + NA16, N_ATM);
    }

    k_pool2<<<N_GRAPHS, 256, 0, stream>>>(h_atm, a.batch, pooled);
    k_head<<<1, 256, 0, stream>>>(pooled, a.fp, a.l1W, a.l1b, a.l2W, a.l2b, flags, d_out);
}

extern "C" void kernel_launch(void* const* d_in, const int* in_sizes, int n_in,
                              void* d_out, int out_size, void* d_ws, size_t ws_size,
                              hipStream_t stream) {
    Args a = unpack(d_in);
    const size_t NA16 = (size_t)N_ATM * 16;
    const size_t NB16 = (size_t)N_BND * 16;
    const size_t NG16 = (size_t)N_ANG * 16;
    const size_t smallB = (64 + 7680 + 192 + 384 + 4096 + 4096) * 4;
    const size_t csrB = ((size_t)N_BND * 2 + (size_t)N_ANG * 2 +
                         (size_t)N_ATM * 2 + (size_t)N_BND * 3) * 4;
    const size_t scratchB = NG16 * 4;  // covers posB union
    const size_t tier1 = smallB + csrB + NA16 * 4 + NB16 * 4 + NG16 * 2 + scratchB; // ~316 MB
    const size_t tier2 = smallB + csrB + NA16 * 4 + NB16 * 2 + NG16 * 2 + scratchB; // ~283 MB
    // atomic fallback: small + h_atm f32 + h_bnd/h_ang bf16 + nd 2*NB16 f32      // ~233 MB
    if (ws_size >= tier1)      run_csr<float>(a, d_out, d_ws, stream);
    else if (ws_size >= tier2) run_csr<bf16>(a, d_out, d_ws, stream);
    else                       run_atomic(a, d_out, d_ws, stream);
}

// Round 9
// 2528.476 us; speedup vs baseline: 6.2982x; 6.2982x over previous
//
#include <hip/hip_runtime.h>
#include <hip/hip_bf16.h>

#define N_ATM 131072
#define N_BND 1048576
#define N_ANG 2097152
#define N_GRAPHS 256
#define D_SPLIT (N_BND / 2)
#define CAP_SLOTS (N_ANG / 2 + 16384)   // line-conv chunk scratch slots (64 B each)
#define PI_F 3.14159265358979323846f

typedef __hip_bfloat16 bf16;

__device__ __forceinline__ int clampi(int v, int lo, int hi) {
    return v < lo ? lo : (v > hi ? hi : v);
}
__device__ __forceinline__ float b2f(bf16 v) { return __bfloat162float(v); }
__device__ __forceinline__ float sigmoidf_(float x) { return 1.0f / (1.0f + __expf(-x)); }
__device__ __forceinline__ float siluf_(float x) { return x / (1.0f + __expf(-x)); }

__device__ __forceinline__ float loadF(const void* p, long long i, int isbf) {
    return isbf ? b2f(((const bf16*)p)[i]) : ((const float*)p)[i];
}
__device__ __forceinline__ float bfbits2f(unsigned lo16) {
    union { unsigned u; float f; } c; c.u = lo16 << 16; return c.f;
}
__device__ __forceinline__ unsigned f2bfbits(float f) {
    union { float f; unsigned u; } c; c.f = f;
    unsigned u = c.u + 0x7FFFu + ((c.u >> 16) & 1u);  // RNE
    return u >> 16;
}

// ---- 16-wide row IO ----
__device__ __forceinline__ void load16f(const float* p, float* r) {
    const float4* q = (const float4*)p;
#pragma unroll
    for (int i = 0; i < 4; i++) { float4 v = q[i]; r[4*i]=v.x; r[4*i+1]=v.y; r[4*i+2]=v.z; r[4*i+3]=v.w; }
}
__device__ __forceinline__ void store16f(float* p, const float* r) {
    float4* q = (float4*)p;
#pragma unroll
    for (int i = 0; i < 4; i++) q[i] = make_float4(r[4*i], r[4*i+1], r[4*i+2], r[4*i+3]);
}
__device__ __forceinline__ void load16b(const bf16* p, float* r) {
    uint4 a = ((const uint4*)p)[0];
    uint4 b = ((const uint4*)p)[1];
    unsigned w[8] = {a.x, a.y, a.z, a.w, b.x, b.y, b.z, b.w};
#pragma unroll
    for (int i = 0; i < 8; i++) {
        r[2*i] = bfbits2f(w[i] & 0xFFFFu);
        union { unsigned u; float f; } c; c.u = w[i] & 0xFFFF0000u;
        r[2*i+1] = c.f;
    }
}
__device__ __forceinline__ void store16b(bf16* p, const float* r) {
    unsigned w[8];
#pragma unroll
    for (int i = 0; i < 8; i++)
        w[i] = f2bfbits(r[2*i]) | (f2bfbits(r[2*i+1]) << 16);
    ((uint4*)p)[0] = make_uint4(w[0], w[1], w[2], w[3]);
    ((uint4*)p)[1] = make_uint4(w[4], w[5], w[6], w[7]);
}

// ---------- utility ----------
__global__ void __launch_bounds__(256) k_zero_int(int* __restrict__ p, int n) {
    int i = blockIdx.x * 256 + threadIdx.x;
    if (i < n) p[i] = 0;
}

// flags[0]=1 if float tensors are bf16; flags[1]=1 if mask is byte-bools
__global__ void __launch_bounds__(256) k_detect(const void* lng, const unsigned* __restrict__ mask,
                                                int* flags) {
    int i = blockIdx.x * 256 + threadIdx.x;
    if (i == 0) flags[0] = (*(const unsigned*)lng == 0x3F803F80u) ? 1 : 0;
    int bad = 0;
    for (int j = i; j < 512 * 1024; j += 512 * 256)
        if (mask[j] > 1u) bad = 1;
    if (bad) atomicOr(&flags[1], 1);
}

__global__ void k_cvt_any(const void* __restrict__ src, float* __restrict__ dst, int n,
                          const int* __restrict__ flags) {
    int i = blockIdx.x * blockDim.x + threadIdx.x;
    if (i < n) dst[i] = loadF(src, i, flags[0]);
}

// ---------- CSR build ----------
__global__ void __launch_bounds__(256) k_count(const int* __restrict__ dst, int* __restrict__ cnt,
                                               int E, int n) {
    int i = blockIdx.x * 256 + threadIdx.x;
    if (i >= E) return;
    atomicAdd(&cnt[clampi(dst[i], 0, n - 1)], 1);
}
__global__ void __launch_bounds__(256) k_scan_local(const int* __restrict__ cnt, int* __restrict__ ofs,
                                                    int* __restrict__ bsum, int n) {
    __shared__ int s[256];
    int t = threadIdx.x, i = blockIdx.x * 256 + t;
    int v = (i < n) ? cnt[i] : 0;
    s[t] = v; __syncthreads();
    for (int o = 1; o < 256; o <<= 1) {
        int add = (t >= o) ? s[t - o] : 0;
        __syncthreads();
        s[t] += add;
        __syncthreads();
    }
    if (i < n) ofs[i] = s[t] - v;
    if (t == 255) bsum[blockIdx.x] = s[255];
}
__global__ void __launch_bounds__(256) k_scan_bsum(int* __restrict__ bsum, int nb) {
    __shared__ int s[256];
    __shared__ int run;
    int t = threadIdx.x;
    if (t == 0) run = 0;
    __syncthreads();
    for (int base = 0; base < nb; base += 256) {
        int i = base + t;
        int v = (i < nb) ? bsum[i] : 0;
        s[t] = v; __syncthreads();
        for (int o = 1; o < 256; o <<= 1) {
            int add = (t >= o) ? s[t - o] : 0;
            __syncthreads();
            s[t] += add;
            __syncthreads();
        }
        if (i < nb) bsum[i] = run + s[t] - v;
        __syncthreads();
        if (t == 0) run += s[255];
        __syncthreads();
    }
}
__global__ void __launch_bounds__(256) k_scan_add(int* __restrict__ ofs, const int* __restrict__ bsum,
                                                  int* __restrict__ cursor, int n) {
    int i = blockIdx.x * 256 + threadIdx.x;
    if (i < n) { int v = ofs[i] + bsum[blockIdx.x]; ofs[i] = v; cursor[i] = v; }
}
// line graph: permuted src/dst + original->slot map
__global__ void __launch_bounds__(256) k_scatter_line(
    const int* __restrict__ src, const int* __restrict__ dst, int* __restrict__ cur,
    int* __restrict__ srcP, int* __restrict__ dstP, int* __restrict__ pos, int E, int n)
{
    int i = blockIdx.x * 256 + threadIdx.x;
    if (i >= E) return;
    int d = clampi(dst[i], 0, n - 1);
    int s = clampi(src[i], 0, n - 1);
    int p = clampi(atomicAdd(&cur[d], 1), 0, E - 1);
    srcP[p] = s; dstP[p] = d; pos[i] = p;
}
// atom graph: slot map only
__global__ void __launch_bounds__(256) k_scatter_pos(
    const int* __restrict__ dst, int* __restrict__ cur, int* __restrict__ pos, int E, int n)
{
    int i = blockIdx.x * 256 + threadIdx.x;
    if (i >= E) return;
    int d = clampi(dst[i], 0, n - 1);
    pos[i] = clampi(atomicAdd(&cur[d], 1), 0, E - 1);
}

// ---------- encoders ----------
__global__ void __launch_bounds__(256) k_enc_atm(
    const int* __restrict__ sp_in,
    const void* W1, const void* b1, const void* W2, const void* b2,
    const void* g, const void* be, const int* __restrict__ flags,
    float* __restrict__ out)
{
    __shared__ float sW1[256], sW2[256], sb1[16], sb2[16], sg[16], sbe[16];
    int t = threadIdx.x, isbf = flags[0];
    sW1[t] = loadF(W1, t, isbf); sW2[t] = loadF(W2, t, isbf);
    if (t < 16) { sb1[t]=loadF(b1,t,isbf); sb2[t]=loadF(b2,t,isbf); sg[t]=loadF(g,t,isbf); sbe[t]=loadF(be,t,isbf); }
    __syncthreads();
    int i = blockIdx.x * 256 + t;
    if (i >= N_ATM) return;
    int sp = clampi(sp_in[i], 0, 15);
    float h[16];
#pragma unroll
    for (int j = 0; j < 16; j++) h[j] = siluf_(sW1[sp * 16 + j] + sb1[j]);
    float o[16]; float mu = 0.f;
#pragma unroll
    for (int j = 0; j < 16; j++) {
        float a = sb2[j];
#pragma unroll
        for (int k = 0; k < 16; k++) a += h[k] * sW2[k * 16 + j];
        o[j] = a; mu += a;
    }
    mu *= (1.f / 16.f);
    float var = 0.f;
#pragma unroll
    for (int j = 0; j < 16; j++) { float d = o[j] - mu; var += d * d; }
    var *= (1.f / 16.f);
    float r = rsqrtf(var + 1e-5f);
    float ov[16];
#pragma unroll
    for (int j = 0; j < 16; j++) ov[j] = (o[j] - mu) * r * sg[j] + sbe[j];
    store16f(out + (long long)i * 16, ov);
}

__global__ void __launch_bounds__(256) k_enc_bnd(
    const void* __restrict__ xb,
    const void* W1, const void* b1, const void* W2, const void* b2,
    const void* g, const void* be, const int* __restrict__ flags,
    bf16* __restrict__ out)
{
    __shared__ float sW1[256], sW2[256], sb1[16], sb2[16], sg[16], sbe[16];
    int t = threadIdx.x, isbf = flags[0];
    sW1[t] = loadF(W1, 256 + t, isbf); sW2[t] = loadF(W2, 256 + t, isbf);
    if (t < 16) { sb1[t]=loadF(b1,16+t,isbf); sb2[t]=loadF(b2,16+t,isbf); sg[t]=loadF(g,16+t,isbf); sbe[t]=loadF(be,16+t,isbf); }
    __syncthreads();
    int i = blockIdx.x * 256 + t;
    if (i >= N_BND) return;
    float x = loadF(xb, i, isbf) + 1e-5f;
    const float c = 0.6324555320336759f; // sqrt(2/5)
    float inv = c / x;
    float feat[16];
#pragma unroll
    for (int k = 0; k < 16; k++) feat[k] = __sinf((float)(k + 1) * PI_F * x * 0.2f) * inv;
    float h[16];
#pragma unroll
    for (int j = 0; j < 16; j++) {
        float a = sb1[j];
#pragma unroll
        for (int k = 0; k < 16; k++) a += feat[k] * sW1[k * 16 + j];
        h[j] = siluf_(a);
    }
    float o[16]; float mu = 0.f;
#pragma unroll
    for (int j = 0; j < 16; j++) {
        float a = sb2[j];
#pragma unroll
        for (int k = 0; k < 16; k++) a += h[k] * sW2[k * 16 + j];
        o[j] = a; mu += a;
    }
    mu *= (1.f / 16.f);
    float var = 0.f;
#pragma unroll
    for (int j = 0; j < 16; j++) { float d = o[j] - mu; var += d * d; }
    var *= (1.f / 16.f);
    float r = rsqrtf(var + 1e-5f);
    float ov[16];
#pragma unroll
    for (int j = 0; j < 16; j++) ov[j] = (o[j] - mu) * r * sg[j] + sbe[j];
    store16b(out + (long long)i * 16, ov);
}

// angle encoder: writes row to CSR slot pos[i]
__global__ void __launch_bounds__(256) k_enc_ang(
    const void* __restrict__ xa, const void* __restrict__ mask,
    const void* W1, const void* b1, const void* W2, const void* b2,
    const void* g, const void* be, const int* __restrict__ flags,
    const int* __restrict__ pos, bf16* __restrict__ out)
{
    __shared__ float sW1[512], sW2[512], sb1[32], sb2[32], sg[32], sbe[32];
    int t = threadIdx.x, isbf = flags[0], mbyte = flags[1];
    for (int i = t; i < 512; i += 256) { sW1[i] = loadF(W1, 512 + i, isbf); sW2[i] = loadF(W2, 512 + i, isbf); }
    if (t < 32) { sb1[t]=loadF(b1,32+t,isbf); sb2[t]=loadF(b2,32+t,isbf); sg[t]=loadF(g,32+t,isbf); sbe[t]=loadF(be,32+t,isbf); }
    __syncthreads();
    int i = blockIdx.x * 256 + t;
    if (i >= N_ANG) return;
    int m = mbyte ? (((const unsigned char*)mask)[i] != 0) : (((const int*)mask)[i] != 0);
    float x = loadF(xa, i, isbf);
    float gam = m ? 2.3873241463784303f : 4.7746482927568605f;   // 15/(2pi) : 15/pi
    float c0  = m ? -PI_F : 0.0f;
    float dc  = m ? 0.41887902047863906f : 0.20943951023931953f; // 2pi/15 : pi/15
    int wo = m * 256, vo = m * 16;
    float feat[16];
#pragma unroll
    for (int k = 0; k < 16; k++) {
        float d = gam * (x - (c0 + (float)k * dc));
        feat[k] = __expf(-d * d);
    }
    float h[16];
#pragma unroll
    for (int j = 0; j < 16; j++) {
        float a = sb1[vo + j];
#pragma unroll
        for (int k = 0; k < 16; k++) a += feat[k] * sW1[wo + k * 16 + j];
        h[j] = siluf_(a);
    }
    float o[16]; float mu = 0.f;
#pragma unroll
    for (int j = 0; j < 16; j++) {
        float a = sb2[vo + j];
#pragma unroll
        for (int k = 0; k < 16; k++) a += h[k] * sW2[wo + k * 16 + j];
        o[j] = a; mu += a;
    }
    mu *= (1.f / 16.f);
    float var = 0.f;
#pragma unroll
    for (int j = 0; j < 16; j++) { float d = o[j] - mu; var += d * d; }
    var *= (1.f / 16.f);
    float r = rsqrtf(var + 1e-5f);
    float ov[16];
#pragma unroll
    for (int j = 0; j < 16; j++) ov[j] = (o[j] - mu) * r * sg[vo + j] + sbe[vo + j];
    store16b(out + (long long)clampi(pos[i], 0, N_ANG - 1) * 16, ov);
}

// ---------- shared edge math ----------
// z = xs@W0 + xd@W1 + ev@W2 + b0; sigma = sig(z); mm = xs@W4
// eo = ev + silu(LN(z)*g+b); wpk = packed {sigma*mm (16 bf16), sigma (16 bf16)}
__device__ __forceinline__ void edge_core(
    const float* xs, const float* xd, const float* ev,
    const float* sW, const float* sB, const float* sLg, const float* sLb,
    float* eo, unsigned* wpk)
{
    float z[16], mm[16];
#pragma unroll
    for (int j = 0; j < 16; j++) { z[j] = sB[j]; mm[j] = 0.f; }
#pragma unroll
    for (int k = 0; k < 16; k++) {
        float a = xs[k], c = xd[k], q = ev[k];
#pragma unroll
        for (int j = 0; j < 16; j++) {
            z[j] += a * sW[k * 16 + j] + c * sW[256 + k * 16 + j] + q * sW[512 + k * 16 + j];
            mm[j] += a * sW[1024 + k * 16 + j];
        }
    }
    float mu = 0.f;
#pragma unroll
    for (int j = 0; j < 16; j++) mu += z[j];
    mu *= (1.f / 16.f);
    float var = 0.f;
#pragma unroll
    for (int j = 0; j < 16; j++) { float dd = z[j] - mu; var += dd * dd; }
    var *= (1.f / 16.f);
    float r = rsqrtf(var + 1e-5f);
#pragma unroll
    for (int j = 0; j < 16; j++)
        eo[j] = ev[j] + siluf_((z[j] - mu) * r * sLg[j] + sLb[j]);
#pragma unroll
    for (int i = 0; i < 8; i++) {
        float a0 = sigmoidf_(z[2*i]);
        float a1 = sigmoidf_(z[2*i+1]);
        wpk[i]     = f2bfbits(a0 * mm[2*i]) | (f2bfbits(a1 * mm[2*i+1]) << 16);
        wpk[8 + i] = f2bfbits(a0)           | (f2bfbits(a1) << 16);
    }
}

// ---------- line conv: edge kernel over slot range [lo, hi) ----------
__global__ void __launch_bounds__(256) k_econv_perm(
    const bf16* __restrict__ x, bf16* __restrict__ e,
    const int* __restrict__ srcP, const int* __restrict__ dstP,
    const float* __restrict__ W, const float* __restrict__ B, const float* __restrict__ L,
    bf16* __restrict__ scratch, const int* __restrict__ loP, const int* __restrict__ hiP,
    int E, int nn)
{
    int blk0 = blockIdx.x * 256;
    int lo = loP ? *loP : 0;
    int hi = hiP ? *hiP : E;
    if (blk0 + 256 <= lo || blk0 >= hi) return;   // uniform early exit (before barrier)
    __shared__ float sW[1280], sB[16], sLg[16], sLb[16];
    int t = threadIdx.x;
    for (int i = t; i < 1280; i += 256) sW[i] = W[i];
    if (t < 16) { sB[t] = B[t]; sLg[t] = L[32 + t]; sLb[t] = L[48 + t]; }
    __syncthreads();
    int p = blk0 + t;
    if (p < lo || p >= hi || p >= E) return;
    int s = clampi(srcP[p], 0, nn - 1);
    int d = clampi(dstP[p], 0, nn - 1);
    float xs[16], xd[16], ev[16];
    load16b(x + (long long)s * 16, xs);
    load16b(x + (long long)d * 16, xd);
    load16b(e + (long long)p * 16, ev);
    float eo[16]; unsigned wpk[16];
    edge_core(xs, xd, ev, sW, sB, sLg, sLb, eo, wpk);
    store16b(e + (long long)p * 16, eo);
    int slot = clampi(p - lo, 0, CAP_SLOTS - 1);
    uint4* sp4 = (uint4*)(scratch + (long long)slot * 32);
    sp4[0] = make_uint4(wpk[0],  wpk[1],  wpk[2],  wpk[3]);
    sp4[1] = make_uint4(wpk[4],  wpk[5],  wpk[6],  wpk[7]);
    sp4[2] = make_uint4(wpk[8],  wpk[9],  wpk[10], wpk[11]);
    sp4[3] = make_uint4(wpk[12], wpk[13], wpk[14], wpk[15]);
}

// ---------- atom conv: edge kernel in natural order ----------
__global__ void __launch_bounds__(256) k_econv_nat(
    const float* __restrict__ x, bf16* __restrict__ e,
    const int* __restrict__ src, const int* __restrict__ dst, const int* __restrict__ pos,
    const float* __restrict__ W, const float* __restrict__ B, const float* __restrict__ L,
    bf16* __restrict__ scratch, int E, int nn)
{
    __shared__ float sW[1280], sB[16], sLg[16], sLb[16];
    int t = threadIdx.x;
    for (int i = t; i < 1280; i += 256) sW[i] = W[i];
    if (t < 16) { sB[t] = B[t]; sLg[t] = L[32 + t]; sLb[t] = L[48 + t]; }
    __syncthreads();
    int i = blockIdx.x * 256 + t;
    if (i >= E) return;
    int s = clampi(src[i], 0, nn - 1);
    int d = clampi(dst[i], 0, nn - 1);
    float xs[16], xd[16], ev[16];
    load16f(x + (long long)s * 16, xs);
    load16f(x + (long long)d * 16, xd);
    load16b(e + (long long)i * 16, ev);
    float eo[16]; unsigned wpk[16];
    edge_core(xs, xd, ev, sW, sB, sLg, sLb, eo, wpk);
    store16b(e + (long long)i * 16, eo);
    int slot = clampi(pos[i], 0, E - 1);
    uint4* sp4 = (uint4*)(scratch + (long long)slot * 32);
    sp4[0] = make_uint4(wpk[0],  wpk[1],  wpk[2],  wpk[3]);
    sp4[1] = make_uint4(wpk[4],  wpk[5],  wpk[6],  wpk[7]);
    sp4[2] = make_uint4(wpk[8],  wpk[9],  wpk[10], wpk[11]);
    sp4[3] = make_uint4(wpk[12], wpk[13], wpk[14], wpk[15]);
}

// ---------- node kernel: segment reduce over scratch; x_old -> x_new ----------
// TX float: load16f/store16f ; TX bf16: load16b/store16b
template <typename TX>
__device__ __forceinline__ void loadRow(const TX* p, float* r);
template <> __device__ __forceinline__ void loadRow<float>(const float* p, float* r) { load16f(p, r); }
template <> __device__ __forceinline__ void loadRow<bf16>(const bf16* p, float* r) { load16b(p, r); }
template <typename TX>
__device__ __forceinline__ void storeRow(TX* p, const float* r);
template <> __device__ __forceinline__ void storeRow<float>(float* p, const float* r) { store16f(p, r); }
template <> __device__ __forceinline__ void storeRow<bf16>(bf16* p, const float* r) { store16b(p, r); }

template <typename TX>
__global__ void __launch_bounds__(256) k_nconv(
    const TX* __restrict__ xo, TX* __restrict__ xn,
    const int* __restrict__ ofs, const int* __restrict__ endo,
    const float* __restrict__ W, const float* __restrict__ B, const float* __restrict__ L,
    const bf16* __restrict__ scratch, const int* __restrict__ baseP,
    int dlo, int dhi, int Emax, int cap)
{
    __shared__ float sW[256], sB[16], sLg[16], sLb[16];
    int t = threadIdx.x;
    sW[t] = W[768 + t];
    if (t < 16) { sB[t] = B[16 + t]; sLg[t] = L[t]; sLb[t] = L[16 + t]; }
    __syncthreads();
    int d = dlo + blockIdx.x * 256 + t;
    if (d >= dhi) return;
    int base = baseP ? *baseP : 0;
    float xv[16];
    loadRow<TX>(xo + (long long)d * 16, xv);
    float num[16], den[16];
#pragma unroll
    for (int j = 0; j < 16; j++) { num[j] = 0.f; den[j] = 0.f; }
    int p0 = clampi(ofs[d], 0, Emax);
    int p1 = clampi(endo[d], p0, Emax);
    for (int p = p0; p < p1; p++) {
        int idx = clampi(p - base, 0, cap - 1);
        const uint4* q = (const uint4*)(scratch + (long long)idx * 32);
        uint4 q0 = q[0], q1 = q[1], q2 = q[2], q3 = q[3];
        unsigned w[16] = {q0.x,q0.y,q0.z,q0.w, q1.x,q1.y,q1.z,q1.w,
                          q2.x,q2.y,q2.z,q2.w, q3.x,q3.y,q3.z,q3.w};
#pragma unroll
        for (int i = 0; i < 8; i++) {
            num[2*i]   += bfbits2f(w[i] & 0xFFFFu);
            num[2*i+1] += bfbits2f(w[i] >> 16);
            den[2*i]   += bfbits2f(w[8+i] & 0xFFFFu);
            den[2*i+1] += bfbits2f(w[8+i] >> 16);
        }
    }
    float tt[16]; float mu = 0.f;
#pragma unroll
    for (int j = 0; j < 16; j++) {
        float a = sB[j] + num[j] / (den[j] + 1e-5f);
#pragma unroll
        for (int k = 0; k < 16; k++) a += xv[k] * sW[k * 16 + j];
        tt[j] = a; mu += a;
    }
    mu *= (1.f / 16.f);
    float var = 0.f;
#pragma unroll
    for (int j = 0; j < 16; j++) { float dd = tt[j] - mu; var += dd * dd; }
    var *= (1.f / 16.f);
    float r = rsqrtf(var + 1e-5f);
    float ov[16];
#pragma unroll
    for (int j = 0; j < 16; j++)
        ov[j] = xv[j] + siluf_((tt[j] - mu) * r * sLg[j] + sLb[j]);
    storeRow<TX>(xn + (long long)d * 16, ov);
}

// ---------- pooling: one block per graph (batch sorted, no atomics) ----------
__global__ void __launch_bounds__(256) k_pool2(
    const float* __restrict__ h, const int* __restrict__ batch, float* __restrict__ pooled)
{
    int g = blockIdx.x;
    int lo = 0, hi = N_ATM;
    while (lo < hi) { int m = (lo + hi) >> 1; if (batch[m] < g) lo = m + 1; else hi = m; }
    int s0 = lo;
    lo = 0; hi = N_ATM;
    while (lo < hi) { int m = (lo + hi) >> 1; if (batch[m] < g + 1) lo = m + 1; else hi = m; }
    int s1 = lo;
    float acc[16];
#pragma unroll
    for (int j = 0; j < 16; j++) acc[j] = 0.f;
    for (int i = s0 + threadIdx.x; i < s1; i += 256) {
        float v[16];
        load16f(h + (long long)i * 16, v);
#pragma unroll
        for (int j = 0; j < 16; j++) acc[j] += v[j];
    }
#pragma unroll
    for (int j = 0; j < 16; j++)
        for (int o = 32; o > 0; o >>= 1) acc[j] += __shfl_down(acc[j], o, 64);
    __shared__ float red[4][16];
    int wv = threadIdx.x >> 6, ln = threadIdx.x & 63;
    if (ln == 0)
#pragma unroll
        for (int j = 0; j < 16; j++) red[wv][j] = acc[j];
    __syncthreads();
    if (threadIdx.x < 16)
        pooled[g * 16 + threadIdx.x] = red[0][threadIdx.x] + red[1][threadIdx.x]
                                     + red[2][threadIdx.x] + red[3][threadIdx.x];
}

// ---------- head ----------
__global__ void __launch_bounds__(256) k_head(
    const float* __restrict__ pooled, const void* __restrict__ fp,
    const void* l1W, const void* l1b, const void* l2W, const void* l2b,
    const int* __restrict__ flags, void* __restrict__ out)
{
    __shared__ float sW[18 * 16], sb[16], s2W[16];
    int t = threadIdx.x, isbf = flags[0];
    for (int i = t; i < 288; i += 256) sW[i] = loadF(l1W, i, isbf);
    if (t < 16) { sb[t] = loadF(l1b, t, isbf); s2W[t] = loadF(l2W, t, isbf); }
    __syncthreads();
    int g = t;
    if (g >= N_GRAPHS) return;
    float in[18];
#pragma unroll
    for (int j = 0; j < 16; j++) in[j] = pooled[g * 16 + j];
    in[16] = loadF(fp, 2 * g, isbf);
    in[17] = loadF(fp, 2 * g + 1, isbf);
    float acc = loadF(l2b, 0, isbf);
#pragma unroll
    for (int j = 0; j < 16; j++) {
        float h = sb[j];
#pragma unroll
        for (int k = 0; k < 18; k++) h += in[k] * sW[k * 16 + j];
        h = (h > 0.f) ? h : 0.01f * h;
        acc += h * s2W[j];
    }
    if (isbf) ((bf16*)out)[g] = __float2bfloat16(acc);
    else      ((float*)out)[g] = acc;
}

extern "C" void kernel_launch(void* const* d_in, const int* in_sizes, int n_in,
                              void* d_out, int out_size, void* d_ws, size_t ws_size,
                              hipStream_t stream) {
    const int*  x_atm = (const int*)d_in[0];
    const void* x_bnd = d_in[1];
    const void* x_ang = d_in[2];
    const void* mask  = d_in[3];
    const int*  eiG   = (const int*)d_in[4];
    const int*  eiA   = (const int*)d_in[5];
    const int*  batch = (const int*)d_in[6];
    const void* fp    = d_in[7];
    const void* eW1 = d_in[8],  *eb1 = d_in[9],  *eW2 = d_in[10], *eb2 = d_in[11];
    const void* elg = d_in[12], *elb = d_in[13];
    const void* convW = d_in[14], *convB = d_in[15], *convLN = d_in[16];
    const void* l1W = d_in[17], *l1b = d_in[18], *l2W = d_in[19], *l2b = d_in[20];

    const size_t NA16 = (size_t)N_ATM * 16;
    const size_t NB16 = (size_t)N_BND * 16;
    const size_t NG16 = (size_t)N_ANG * 16;

    // Workspace layout — total 241,238,528 B (proven-safe vs R8's 243.3 MB success)
    char* p = (char*)d_ws;
    int*   flags  = (int*)p;   p += 256;
    float* cw     = (float*)p; p += 7680 * 4;
    float* cb     = (float*)p; p += 192 * 4;
    float* cln    = (float*)p; p += 384 * 4;
    float* pooled = (float*)p; p += 4096 * 4;
    int*   bsum   = (int*)p;   p += 4096 * 4;
    int*   cntB   = (int*)p;   p += (size_t)N_BND * 4;   // start cursor -> end
    int*   ofsB   = (int*)p;   p += (size_t)N_BND * 4;
    int*   srcB   = (int*)p;   p += (size_t)N_ANG * 4;
    int*   dstB   = (int*)p;   p += (size_t)N_ANG * 4;
    int*   cntA   = (int*)p;   p += (size_t)N_ATM * 4;
    int*   ofsA   = (int*)p;   p += (size_t)N_ATM * 4;
    int*   posG   = (int*)p;   p += (size_t)N_BND * 4;
    float* h_atm  = (float*)p; p += NA16 * 4;
    bf16*  h_bndX = (bf16*)p;  p += NB16 * 2;
    bf16*  h_bndY = (bf16*)p;  p += NB16 * 2;
    bf16*  h_ang  = (bf16*)p;  p += NG16 * 2;
    int*   posB    = (int*)p;            // union: posB dead after encoding,
    bf16*  scratch = (bf16*)p;           // scratch born in conv loop (CAP_SLOTS*64 B)

    // dtype detection + conv params
    k_zero_int<<<1, 64, 0, stream>>>(flags, 64);
    k_detect<<<512, 256, 0, stream>>>(elg, (const unsigned*)mask, flags);
    k_cvt_any<<<30, 256, 0, stream>>>(convW, cw, 7680, flags);
    k_cvt_any<<<1, 256, 0, stream>>>(convB, cb, 192, flags);
    k_cvt_any<<<2, 256, 0, stream>>>(convLN, cln, 384, flags);

    // CSR: line graph (bonds <- angle edges)
    k_zero_int<<<N_BND / 256, 256, 0, stream>>>(cntB, N_BND);
    k_count<<<N_ANG / 256, 256, 0, stream>>>(eiA + N_ANG, cntB, N_ANG, N_BND);
    k_scan_local<<<N_BND / 256, 256, 0, stream>>>(cntB, ofsB, bsum, N_BND);
    k_scan_bsum<<<1, 256, 0, stream>>>(bsum, N_BND / 256);
    k_scan_add<<<N_BND / 256, 256, 0, stream>>>(ofsB, bsum, cntB, N_BND);
    k_scatter_line<<<N_ANG / 256, 256, 0, stream>>>(eiA, eiA + N_ANG, cntB, srcB, dstB, posB,
                                                    N_ANG, N_BND);
    // CSR: atom graph (atoms <- bond edges)
    k_zero_int<<<N_ATM / 256, 256, 0, stream>>>(cntA, N_ATM);
    k_count<<<N_BND / 256, 256, 0, stream>>>(eiG + N_BND, cntA, N_BND, N_ATM);
    k_scan_local<<<N_ATM / 256, 256, 0, stream>>>(cntA, ofsA, bsum, N_ATM);
    k_scan_bsum<<<1, 256, 0, stream>>>(bsum, N_ATM / 256);
    k_scan_add<<<N_ATM / 256, 256, 0, stream>>>(ofsA, bsum, cntA, N_ATM);
    k_scatter_pos<<<N_BND / 256, 256, 0, stream>>>(eiG + N_BND, cntA, posG, N_BND, N_ATM);

    // encoders (k_enc_ang consumes posB; scratch reuses that region afterwards)
    k_enc_atm<<<N_ATM / 256, 256, 0, stream>>>(x_atm, eW1, eb1, eW2, eb2, elg, elb, flags, h_atm);
    k_enc_bnd<<<N_BND / 256, 256, 0, stream>>>(x_bnd, eW1, eb1, eW2, eb2, elg, elb, flags, h_bndX);
    k_enc_ang<<<N_ANG / 256, 256, 0, stream>>>(x_ang, mask, eW1, eb1, eW2, eb2, elg, elb, flags,
                                               posB, h_ang);

    // processor: 3x (line conv chunked in 2 node-ranges; atom conv full)
    bf16* X = h_bndX;
    bf16* Y = h_bndY;
    const int* split = ofsB + D_SPLIT;   // slot boundary between node chunks
    for (int c = 0; c < 3; c++) {
        const float* Wl = cw + (size_t)(c * 2 + 0) * 1280;
        const float* Bl = cb + (size_t)(c * 2 + 0) * 32;
        const float* Ll = cln + (size_t)(c * 2 + 0) * 64;
        // chunk 1: slots [0, split), nodes [0, D_SPLIT)
        k_econv_perm<<<N_ANG / 256, 256, 0, stream>>>(X, h_ang, srcB, dstB, Wl, Bl, Ll,
                                                      scratch, (const int*)nullptr, split,
                                                      N_ANG, N_BND);
        k_nconv<bf16><<<D_SPLIT / 256, 256, 0, stream>>>(X, Y, ofsB, cntB, Wl, Bl, Ll,
                                                         scratch, (const int*)nullptr,
                                                         0, D_SPLIT, N_ANG, CAP_SLOTS);
        // chunk 2: slots [split, E), nodes [D_SPLIT, N_BND)  (edge pass reads OLD X)
        k_econv_perm<<<N_ANG / 256, 256, 0, stream>>>(X, h_ang, srcB, dstB, Wl, Bl, Ll,
                                                      scratch, split, (const int*)nullptr,
                                                      N_ANG, N_BND);
        k_nconv<bf16><<<(N_BND - D_SPLIT) / 256, 256, 0, stream>>>(X, Y, ofsB, cntB, Wl, Bl, Ll,
                                                                   scratch, split,
                                                                   D_SPLIT, N_BND, N_ANG, CAP_SLOTS);
        // atom conv: e = updated bonds (Y, in place), x = h_atm (in place)
        const float* Wa = cw + (size_t)(c * 2 + 1) * 1280;
        const float* Ba = cb + (size_t)(c * 2 + 1) * 32;
        const float* La = cln + (size_t)(c * 2 + 1) * 64;
        k_econv_nat<<<N_BND / 256, 256, 0, stream>>>(h_atm, Y, eiG, eiG + N_BND, posG,
                                                     Wa, Ba, La, scratch, N_BND, N_ATM);
        k_nconv<float><<<N_ATM / 256, 256, 0, stream>>>(h_atm, h_atm, ofsA, cntA, Wa, Ba, La,
                                                        scratch, (const int*)nullptr,
                                                        0, N_ATM, N_BND, N_BND);
        bf16* tmp = X; X = Y; Y = tmp;
    }

    k_pool2<<<N_GRAPHS, 256, 0, stream>>>(h_atm, batch, pooled);
    k_head<<<1, 256, 0, stream>>>(pooled, fp, l1W, l1b, l2W, l2b, flags, d_out);
}